// Round 6
// baseline (235.021 us; speedup 1.0000x reference)
//
#include <hip/hip_runtime.h>

// Problem constants (from reference setup_inputs)
constexpr int GRID_D = 128;
constexpr int BATCHN = 4;
constexpr int C = 64;
constexpr int VOL = GRID_D * GRID_D * GRID_D;      // 2,097,152
constexpr int V = BATCHN * VOL;                    // 8,388,608 voxel ids
constexpr int W = V / 32;                          // 262,144 bitmask words
constexpr int SCAN_BS = 1024;                      // threads per scan block
constexpr int SCAN_NB = W / SCAN_BS;               // 256 scan blocks

// clang native vector type (works with __builtin_nontemporal_*)
typedef float floatx4 __attribute__((ext_vector_type(4)));

// ---------------- kernels ----------------

// Zero the [cnt | ovfCnt | bm] region (count uint4s)
__global__ void zero_ws(uint4* __restrict__ p, int count) {
    int i = blockIdx.x * blockDim.x + threadIdx.x;
    if (i < count) p[i] = uint4{0u, 0u, 0u, 0u};
}

// Mark each point's voxel id in the bitmask; store lin[] for later passes.
__global__ void mark_bits(const int* __restrict__ coords, unsigned* __restrict__ bm,
                          unsigned* __restrict__ lin, int n) {
    int i = blockIdx.x * blockDim.x + threadIdx.x;
    if (i >= n) return;
    int4 co = reinterpret_cast<const int4*>(coords)[i];
    unsigned l = (unsigned)(co.w * VOL + co.x * (GRID_D * GRID_D) + co.y * GRID_D + co.z);
    lin[i] = l;
    atomicOr(&bm[l >> 5], 1u << (l & 31));
}

// Level-1 scan: per-block exclusive scan of popcounts (wp stays block-local);
// block totals to bs[]
__global__ void scan1(const unsigned* __restrict__ bm, unsigned* __restrict__ wp,
                      unsigned* __restrict__ bs) {
    int idx = blockIdx.x * SCAN_BS + threadIdx.x;
    unsigned pc = __popc(bm[idx]);
    unsigned v = pc;
    #pragma unroll
    for (int d = 1; d < 64; d <<= 1) {
        unsigned t = __shfl_up(v, d, 64);
        if ((threadIdx.x & 63) >= d) v += t;
    }
    __shared__ unsigned wsum[16];
    int wid = threadIdx.x >> 6;
    int lane = threadIdx.x & 63;
    if (lane == 63) wsum[wid] = v;
    __syncthreads();
    if (threadIdx.x < 16) {
        unsigned s = wsum[threadIdx.x];
        #pragma unroll
        for (int d = 1; d < 16; d <<= 1) {
            unsigned t = __shfl_up(s, d, 16);
            if ((threadIdx.x & 15) >= d) s += t;
        }
        wsum[threadIdx.x] = s;  // inclusive wave totals
    }
    __syncthreads();
    unsigned waveoff = (wid == 0) ? 0u : wsum[wid - 1];
    wp[idx] = waveoff + v - pc;                       // exclusive within block
    if (threadIdx.x == SCAN_BS - 1) bs[blockIdx.x] = waveoff + v;  // block total
}

// Level-2 scan: exclusive scan of the 256 block totals in place; grand total -> bs[256]
__global__ void scan2(unsigned* bs) {
    int t = threadIdx.x;  // 256 threads
    unsigned pc = bs[t];
    unsigned v = pc;
    #pragma unroll
    for (int d = 1; d < 64; d <<= 1) {
        unsigned tt = __shfl_up(v, d, 64);
        if ((t & 63) >= d) v += tt;
    }
    __shared__ unsigned wsum[4];
    int wid = t >> 6, lane = t & 63;
    if (lane == 63) wsum[wid] = v;
    __syncthreads();
    if (t < 4) {
        unsigned s = wsum[t];
        #pragma unroll
        for (int d = 1; d < 4; d <<= 1) {
            unsigned tt = __shfl_up(s, d, 4);
            if ((t & 3) >= d) s += tt;
        }
        wsum[t] = s;
    }
    __syncthreads();
    unsigned waveoff = (wid == 0) ? 0u : wsum[wid - 1];
    bs[t] = waveoff + v - pc;          // exclusive block offsets
    if (t == SCAN_NB - 1) bs[SCAN_NB] = waveoff + v;  // grand total = unique count
}

// Emit sorted unique ids (as float) at their ranks
__global__ void emit_uniq(const unsigned* __restrict__ bm, const unsigned* __restrict__ wp,
                          const unsigned* __restrict__ bs, float* __restrict__ out) {
    int idx = blockIdx.x * blockDim.x + threadIdx.x;
    unsigned word = bm[idx];
    unsigned base = wp[idx] + bs[idx >> 10];
    while (word) {
        int b = __ffs(word) - 1;
        out[base++] = (float)((idx << 5) + b);
        word &= word - 1;
    }
}

// Per point: compute rank, register as contributor. First two contributors go
// to slot0/slot1; the rare rest (voxels with >=3 points) go to the overflow list.
__global__ void rank_slot(const unsigned* __restrict__ lin, const unsigned* __restrict__ bm,
                          const unsigned* __restrict__ wp, const unsigned* __restrict__ bs,
                          unsigned* __restrict__ cnt, unsigned* __restrict__ slot0,
                          unsigned* __restrict__ slot1, uint2* __restrict__ ovf,
                          unsigned* __restrict__ ovfCnt, int n) {
    int i = blockIdx.x * blockDim.x + threadIdx.x;
    if (i >= n) return;
    unsigned l = lin[i];
    unsigned w = l >> 5, b = l & 31;
    unsigned rank = wp[w] + bs[w >> 10] + __popc(bm[w] & ((1u << b) - 1u));
    unsigned old = atomicAdd(&cnt[rank], 1u);
    if (old == 0) slot0[rank] = (unsigned)i;
    else if (old == 1) slot1[rank] = (unsigned)i;
    else {
        unsigned o = atomicAdd(ovfCnt, 1u);
        ovf[o] = uint2{rank, (unsigned)i};
    }
}

// Gather: 16 threads per rank (one floatx4 each). Sequential nontemporal writes;
// random nontemporal 256B reads from feat. Ranks >= total (cnt==0) write zero
// rows and the -1 id padding.
__global__ void gather_feat(const floatx4* __restrict__ feat4, const unsigned* __restrict__ cnt,
                            const unsigned* __restrict__ slot0, const unsigned* __restrict__ slot1,
                            float* __restrict__ out_ids, float* __restrict__ outf, int n) {
    int gid = blockIdx.x * blockDim.x + threadIdx.x;
    int rank = gid >> 4;
    int c4 = gid & 15;
    if (rank >= n) return;
    unsigned c = cnt[rank];
    floatx4 v = {0.f, 0.f, 0.f, 0.f};
    if (c >= 1) {
        unsigned p0 = slot0[rank];
        v = __builtin_nontemporal_load(&feat4[(size_t)p0 * 16 + c4]);
        if (c >= 2) {
            unsigned p1 = slot1[rank];
            floatx4 u = __builtin_nontemporal_load(&feat4[(size_t)p1 * 16 + c4]);
            v.x += u.x; v.y += u.y; v.z += u.z; v.w += u.w;
        }
    } else if (c4 == 0) {
        out_ids[rank] = -1.0f;  // tail id padding
    }
    __builtin_nontemporal_store(v, reinterpret_cast<floatx4*>(outf + (size_t)rank * C + c4 * 4));
}

// Apply the rare >=3rd contributors by atomicAdd (runs after gather's stores).
__global__ void ovf_apply(const uint2* __restrict__ ovf, const unsigned* __restrict__ ovfCnt,
                          const floatx4* __restrict__ feat4, float* __restrict__ outf) {
    unsigned m = *ovfCnt;
    unsigned stride = gridDim.x * blockDim.x;
    for (unsigned idx = blockIdx.x * blockDim.x + threadIdx.x; idx < m * 16; idx += stride) {
        unsigned e = idx >> 4, c4 = idx & 15;
        uint2 rp = ovf[e];
        floatx4 v = feat4[(size_t)rp.y * 16 + c4];
        float* dst = outf + (size_t)rp.x * C + c4 * 4;
        atomicAdd(dst + 0, v.x);
        atomicAdd(dst + 1, v.y);
        atomicAdd(dst + 2, v.z);
        atomicAdd(dst + 3, v.w);
    }
}

// ---------------- launch ----------------

extern "C" void kernel_launch(void* const* d_in, const int* in_sizes, int n_in,
                              void* d_out, int out_size, void* d_ws, size_t ws_size,
                              hipStream_t stream) {
    const int* coords = (const int*)d_in[0];
    const float* feat = (const float*)d_in[1];
    int n = in_sizes[0] / 4;  // N points

    float* out_ids = (float*)d_out;            // [n] unique ids (float), -1 padded
    float* out_feat = (float*)d_out + n;       // [n][C] scattered features

    // ws layout (words). Zeroed region first: [cnt | ovfCnt | bm]
    unsigned* cnt = (unsigned*)d_ws;           // n words
    unsigned* ovfCnt = cnt + n;                // 64 words (1 used)
    unsigned* bm = ovfCnt + 64;                // W words
    unsigned* wp = bm + W;                     // W words (block-local prefix)
    unsigned* bs = wp + W;                     // SCAN_NB+1 (+pad) words
    unsigned* lin = bs + SCAN_NB + 64;         // n words
    unsigned* slot0 = lin + n;                 // n words
    unsigned* slot1 = slot0 + n;               // n words
    uint2* ovf = (uint2*)(slot1 + n);          // up to n entries

    int zero_words = n + 64 + W;               // multiple of 4
    int zero_u4 = zero_words / 4;
    zero_ws<<<(zero_u4 + 255) / 256, 256, 0, stream>>>((uint4*)d_ws, zero_u4);

    mark_bits<<<(n + 255) / 256, 256, 0, stream>>>(coords, bm, lin, n);
    scan1<<<SCAN_NB, SCAN_BS, 0, stream>>>(bm, wp, bs);
    scan2<<<1, SCAN_NB, 0, stream>>>(bs);
    emit_uniq<<<W / 256, 256, 0, stream>>>(bm, wp, bs, out_ids);
    rank_slot<<<(n + 255) / 256, 256, 0, stream>>>(lin, bm, wp, bs, cnt, slot0, slot1,
                                                   ovf, ovfCnt, n);
    gather_feat<<<(n * 16) / 256, 256, 0, stream>>>((const floatx4*)feat, cnt, slot0, slot1,
                                                    out_ids, out_feat, n);
    ovf_apply<<<128, 256, 0, stream>>>(ovf, ovfCnt, (const floatx4*)feat, out_feat);
}

// Round 7
// 231.276 us; speedup vs baseline: 1.0162x; 1.0162x over previous
//
#include <hip/hip_runtime.h>

// Problem constants (from reference setup_inputs)
constexpr int GRID_D = 128;
constexpr int BATCHN = 4;
constexpr int C = 64;
constexpr int VOL = GRID_D * GRID_D * GRID_D;      // 2,097,152
constexpr int V = BATCHN * VOL;                    // 8,388,608 voxel ids
constexpr int W = V / 32;                          // 262,144 bitmask words
constexpr int SCAN_BS = 1024;                      // threads per scan block
constexpr int SCAN_NB = W / SCAN_BS;               // 256 scan blocks

// clang native vector type (works with __builtin_nontemporal_*)
typedef float floatx4 __attribute__((ext_vector_type(4)));

// ---------------- kernels ----------------

// Zero the [meta | ovfCnt | bm] region (count uint4s)
__global__ void zero_ws(uint4* __restrict__ p, int count) {
    int i = blockIdx.x * blockDim.x + threadIdx.x;
    if (i < count) p[i] = uint4{0u, 0u, 0u, 0u};
}

// Mark each point's voxel id in the bitmask; store lin[] for later passes.
__global__ void mark_bits(const int* __restrict__ coords, unsigned* __restrict__ bm,
                          unsigned* __restrict__ lin, int n) {
    int i = blockIdx.x * blockDim.x + threadIdx.x;
    if (i >= n) return;
    int4 co = reinterpret_cast<const int4*>(coords)[i];
    unsigned l = (unsigned)(co.w * VOL + co.x * (GRID_D * GRID_D) + co.y * GRID_D + co.z);
    lin[i] = l;
    atomicOr(&bm[l >> 5], 1u << (l & 31));
}

// Level-1 scan: per-block exclusive scan of popcounts (wp stays block-local);
// block totals to bs[]
__global__ void scan1(const unsigned* __restrict__ bm, unsigned* __restrict__ wp,
                      unsigned* __restrict__ bs) {
    int idx = blockIdx.x * SCAN_BS + threadIdx.x;
    unsigned pc = __popc(bm[idx]);
    unsigned v = pc;
    #pragma unroll
    for (int d = 1; d < 64; d <<= 1) {
        unsigned t = __shfl_up(v, d, 64);
        if ((threadIdx.x & 63) >= d) v += t;
    }
    __shared__ unsigned wsum[16];
    int wid = threadIdx.x >> 6;
    int lane = threadIdx.x & 63;
    if (lane == 63) wsum[wid] = v;
    __syncthreads();
    if (threadIdx.x < 16) {
        unsigned s = wsum[threadIdx.x];
        #pragma unroll
        for (int d = 1; d < 16; d <<= 1) {
            unsigned t = __shfl_up(s, d, 16);
            if ((threadIdx.x & 15) >= d) s += t;
        }
        wsum[threadIdx.x] = s;  // inclusive wave totals
    }
    __syncthreads();
    unsigned waveoff = (wid == 0) ? 0u : wsum[wid - 1];
    wp[idx] = waveoff + v - pc;                       // exclusive within block
    if (threadIdx.x == SCAN_BS - 1) bs[blockIdx.x] = waveoff + v;  // block total
}

// Level-2 scan: exclusive scan of the 256 block totals in place; grand total -> bs[256]
__global__ void scan2(unsigned* bs) {
    int t = threadIdx.x;  // 256 threads
    unsigned pc = bs[t];
    unsigned v = pc;
    #pragma unroll
    for (int d = 1; d < 64; d <<= 1) {
        unsigned tt = __shfl_up(v, d, 64);
        if ((t & 63) >= d) v += tt;
    }
    __shared__ unsigned wsum[4];
    int wid = t >> 6, lane = t & 63;
    if (lane == 63) wsum[wid] = v;
    __syncthreads();
    if (t < 4) {
        unsigned s = wsum[t];
        #pragma unroll
        for (int d = 1; d < 4; d <<= 1) {
            unsigned tt = __shfl_up(s, d, 4);
            if ((t & 3) >= d) s += tt;
        }
        wsum[t] = s;
    }
    __syncthreads();
    unsigned waveoff = (wid == 0) ? 0u : wsum[wid - 1];
    bs[t] = waveoff + v - pc;          // exclusive block offsets
    if (t == SCAN_NB - 1) bs[SCAN_NB] = waveoff + v;  // grand total = unique count
}

// Emit sorted unique ids (as float) at their ranks
__global__ void emit_uniq(const unsigned* __restrict__ bm, const unsigned* __restrict__ wp,
                          const unsigned* __restrict__ bs, float* __restrict__ out) {
    int idx = blockIdx.x * blockDim.x + threadIdx.x;
    unsigned word = bm[idx];
    unsigned base = wp[idx] + bs[idx >> 10];
    while (word) {
        int b = __ffs(word) - 1;
        out[base++] = (float)((idx << 5) + b);
        word &= word - 1;
    }
}

// Per point: compute rank, register as contributor in meta[rank] = {cnt, p0, p1, -}.
// First two contributors go to .y/.z; the rare rest (>=3 per voxel) overflow.
__global__ void rank_slot(const unsigned* __restrict__ lin, const unsigned* __restrict__ bm,
                          const unsigned* __restrict__ wp, const unsigned* __restrict__ bs,
                          unsigned* __restrict__ metau, uint2* __restrict__ ovf,
                          unsigned* __restrict__ ovfCnt, int n) {
    int i = blockIdx.x * blockDim.x + threadIdx.x;
    if (i >= n) return;
    unsigned l = lin[i];
    unsigned w = l >> 5, b = l & 31;
    unsigned rank = wp[w] + bs[w >> 10] + __popc(bm[w] & ((1u << b) - 1u));
    unsigned old = atomicAdd(&metau[rank * 4], 1u);
    if (old == 0) metau[rank * 4 + 1] = (unsigned)i;
    else if (old == 1) metau[rank * 4 + 2] = (unsigned)i;
    else {
        unsigned o = atomicAdd(ovfCnt, 1u);
        ovf[o] = uint2{rank, (unsigned)i};
    }
}

// Gather: 16 threads per rank (one floatx4 each), grid-strided (4 iters/thread).
// One 16B broadcast meta load -> both feat loads issue independently.
// Sequential nontemporal writes; plain cached random 256B reads.
__global__ void gather_feat(const floatx4* __restrict__ feat4, const uint4* __restrict__ meta,
                            float* __restrict__ out_ids, float* __restrict__ outf, int n) {
    int stride = gridDim.x * blockDim.x;
    int total = n * 16;
    for (int gid = blockIdx.x * blockDim.x + threadIdx.x; gid < total; gid += stride) {
        int rank = gid >> 4;
        int c4 = gid & 15;
        uint4 m = meta[rank];
        floatx4 v = {0.f, 0.f, 0.f, 0.f};
        if (m.x >= 1) {
            v = feat4[(size_t)m.y * 16 + c4];
            if (m.x >= 2) {
                floatx4 u = feat4[(size_t)m.z * 16 + c4];
                v += u;
            }
        } else if (c4 == 0) {
            out_ids[rank] = -1.0f;  // tail id padding
        }
        __builtin_nontemporal_store(v, reinterpret_cast<floatx4*>(outf + (size_t)rank * C + c4 * 4));
    }
}

// Apply the rare >=3rd contributors by atomicAdd (runs after gather's stores).
__global__ void ovf_apply(const uint2* __restrict__ ovf, const unsigned* __restrict__ ovfCnt,
                          const floatx4* __restrict__ feat4, float* __restrict__ outf) {
    unsigned m = *ovfCnt;
    unsigned stride = gridDim.x * blockDim.x;
    for (unsigned idx = blockIdx.x * blockDim.x + threadIdx.x; idx < m * 16; idx += stride) {
        unsigned e = idx >> 4, c4 = idx & 15;
        uint2 rp = ovf[e];
        floatx4 v = feat4[(size_t)rp.y * 16 + c4];
        float* dst = outf + (size_t)rp.x * C + c4 * 4;
        atomicAdd(dst + 0, v.x);
        atomicAdd(dst + 1, v.y);
        atomicAdd(dst + 2, v.z);
        atomicAdd(dst + 3, v.w);
    }
}

// ---------------- launch ----------------

extern "C" void kernel_launch(void* const* d_in, const int* in_sizes, int n_in,
                              void* d_out, int out_size, void* d_ws, size_t ws_size,
                              hipStream_t stream) {
    const int* coords = (const int*)d_in[0];
    const float* feat = (const float*)d_in[1];
    int n = in_sizes[0] / 4;  // N points

    float* out_ids = (float*)d_out;            // [n] unique ids (float), -1 padded
    float* out_feat = (float*)d_out + n;       // [n][C] scattered features

    // ws layout (words). Zeroed region first: [meta | ovfCnt | bm]
    unsigned* metau = (unsigned*)d_ws;         // 4n words: {cnt,p0,p1,-} per rank
    unsigned* ovfCnt = metau + 4 * (size_t)n;  // 64 words (1 used)
    unsigned* bm = ovfCnt + 64;                // W words
    unsigned* wp = bm + W;                     // W words (block-local prefix)
    unsigned* bs = wp + W;                     // SCAN_NB+1 (+pad) words
    unsigned* lin = bs + SCAN_NB + 64;         // n words
    uint2* ovf = (uint2*)(lin + n);            // up to n entries

    size_t zero_words = 4 * (size_t)n + 64 + W;
    int zero_u4 = (int)(zero_words / 4);
    zero_ws<<<(zero_u4 + 255) / 256, 256, 0, stream>>>((uint4*)d_ws, zero_u4);

    mark_bits<<<(n + 255) / 256, 256, 0, stream>>>(coords, bm, lin, n);
    scan1<<<SCAN_NB, SCAN_BS, 0, stream>>>(bm, wp, bs);
    scan2<<<1, SCAN_NB, 0, stream>>>(bs);
    emit_uniq<<<W / 256, 256, 0, stream>>>(bm, wp, bs, out_ids);
    rank_slot<<<(n + 255) / 256, 256, 0, stream>>>(lin, bm, wp, bs, metau, ovf, ovfCnt, n);
    gather_feat<<<16384, 256, 0, stream>>>((const floatx4*)feat, (const uint4*)metau,
                                           out_ids, out_feat, n);
    ovf_apply<<<128, 256, 0, stream>>>(ovf, ovfCnt, (const floatx4*)feat, out_feat);
}